// Round 7
// baseline (75.097 us; speedup 1.0000x reference)
//
#include <hip/hip_runtime.h>
#include <hip/hip_bf16.h>

// B=128, LQ=32, LD=256, HID=768, DIM=128
typedef __attribute__((ext_vector_type(8))) short short8;
typedef __attribute__((ext_vector_type(4))) float f32x4;
typedef __attribute__((ext_vector_type(16))) float f32x16;

#define MFMA16(a, b, c) __builtin_amdgcn_mfma_f32_16x16x32_bf16(a, b, c, 0, 0, 0)
#define MFMA32(a, b, c) __builtin_amdgcn_mfma_f32_32x32x16_bf16(a, b, c, 0, 0, 0)

__device__ __forceinline__ short f2bf(float f) {
    union { float f; unsigned u; } x; x.f = f;
    unsigned r = x.u + 0x7fffu + ((x.u >> 16) & 1u);  // RNE
    return (short)(r >> 16);
}

__device__ __forceinline__ short8 cvt8(const float4& a, const float4& b) {
    short8 v;
    v[0]=f2bf(a.x); v[1]=f2bf(a.y); v[2]=f2bf(a.z); v[3]=f2bf(a.w);
    v[4]=f2bf(b.x); v[5]=f2bf(b.y); v[6]=f2bf(b.z); v[7]=f2bf(b.w);
    return v;
}

// ---------------------------------------------------------------------------
// Kernel 0 (unchanged): W [128x768] fp32 -> bf16 B-fragment image.
// Slot gt=(kc*16+f)*64+lane (f=ks*8+n) holds frag elem: dim=(f&7)*16+(lane&15),
// k=kc*64+(f>>3)*32+(lane>>4)*8+j. One dwordx4 per wave-frag, coalesced.
// ---------------------------------------------------------------------------
__global__ __launch_bounds__(256) void wprep_kernel(
    const float* __restrict__ W, unsigned short* __restrict__ Wimg)
{
    const int gt = blockIdx.x * 256 + threadIdx.x;    // 0..12287
    const int kc = gt >> 10, rem = gt & 1023;
    const int f = rem >> 6, lane = rem & 63;
    const int dim = (f & 7) * 16 + (lane & 15);
    const int kb  = kc * 64 + (f >> 3) * 32 + (lane >> 4) * 8;
    const float4* s = reinterpret_cast<const float4*>(W + dim * 768 + kb);
    float4 a = s[0], b = s[1];
    *reinterpret_cast<short8*>(Wimg + (size_t)gt * 8) = cvt8(a, b);
}

// ---------------------------------------------------------------------------
// Kernel 1 (REWRITTEN): P[row][dim] = l2norm(X[row] @ W^T), bf16 out.
// ONE WAVE per 16-row strip. NO LDS, NO barriers. A-frags: lane-local direct
// global loads of X (dense 64B lines). B-frags: coalesced dwordx4 from the
// L1/L2-resident Wimg. Next-chunk X prefetched in regs. 2304 independent
// waves -> 9 waves/CU, latency hidden by TLP+MLP, no barrier drains.
// ---------------------------------------------------------------------------
__global__ __launch_bounds__(64) void proj_norm_kernel(
    const float* __restrict__ qh, const float* __restrict__ dh,
    const unsigned short* __restrict__ Wimg, const int* __restrict__ dmask,
    unsigned short* __restrict__ Qb, unsigned short* __restrict__ Db)
{
    const int lane = threadIdx.x;
    const int l = lane & 15, g = lane >> 4;

    const int rowbase = blockIdx.x * 16;        // strips: Q = 0..255, D = 256..2303
    const bool isQ = rowbase < 4096;
    const float* X = isQ ? qh : dh;
    const int prow = isQ ? rowbase : rowbase - 4096;

    const float* xp = X + (size_t)(prow + l) * 768 + g * 8;   // lane-local row
    const unsigned short* wp = Wimg + lane * 8;

    f32x4 acc[8];
    #pragma unroll
    for (int n = 0; n < 8; ++n) acc[n] = (f32x4)(0.0f);

    float4 xc[4], xn[4];
    #pragma unroll
    for (int i = 0; i < 4; ++i)
        xc[i] = *reinterpret_cast<const float4*>(xp + (i >> 1) * 32 + (i & 1) * 4);

    for (int kc = 0; kc < 12; ++kc) {
        // prefetch next chunk's X (4 dwordx4, in flight across this chunk's MFMAs)
        if (kc < 11) {
            const float* nx = xp + (kc + 1) * 64;
            #pragma unroll
            for (int i = 0; i < 4; ++i)
                xn[i] = *reinterpret_cast<const float4*>(nx + (i >> 1) * 32 + (i & 1) * 4);
        }
        // B-frags for this chunk: 16 coalesced dwordx4 from Wimg (L1/L2-hot)
        short8 wf[16];
        #pragma unroll
        for (int f = 0; f < 16; ++f)
            wf[f] = *reinterpret_cast<const short8*>(wp + (kc * 16 + f) * 512);

        short8 af0 = cvt8(xc[0], xc[1]);    // ks = 0
        short8 af1 = cvt8(xc[2], xc[3]);    // ks = 1
        #pragma unroll
        for (int n = 0; n < 8; ++n) acc[n] = MFMA16(af0, wf[n], acc[n]);
        #pragma unroll
        for (int n = 0; n < 8; ++n) acc[n] = MFMA16(af1, wf[8 + n], acc[n]);

        #pragma unroll
        for (int i = 0; i < 4; ++i) xc[i] = xn[i];
    }

    // --- L2 norm: lane holds C[row=g*4+r][dim=n*16+l] in acc[n][r] ---
    #pragma unroll
    for (int r = 0; r < 4; ++r) {
        float ss = 0.f;
        #pragma unroll
        for (int n = 0; n < 8; ++n) ss += acc[n][r] * acc[n][r];
        ss += __shfl_xor(ss, 1);
        ss += __shfl_xor(ss, 2);
        ss += __shfl_xor(ss, 4);
        ss += __shfl_xor(ss, 8);
        float rn = rsqrtf(ss);
        const int row = prow + g * 4 + r;
        if (!isQ && dmask[row] == 0) rn = 0.f;  // zero masked doc tokens
        unsigned short* P = isQ ? Qb : Db;
        #pragma unroll
        for (int n = 0; n < 8; ++n)
            P[(size_t)row * 128 + n * 16 + l] = (unsigned short)f2bf(acc[n][r] * rn);
    }
}

// ---------------------------------------------------------------------------
// Kernel 1.5 (unchanged): in-place per-doc compaction of Db; valid rows first,
// padding duplicates token 0 (always valid; duplicates can't change a max).
// ---------------------------------------------------------------------------
__global__ __launch_bounds__(256) void compact_kernel(
    const int* __restrict__ dmask, unsigned short* __restrict__ Db)
{
    __shared__ __align__(16) short rows[256][128];
    __shared__ int wcnt[4];

    const int c = blockIdx.x;
    const int tid = threadIdx.x;
    const int wave = tid >> 6, lane = tid & 63;

    short8* ldsf = reinterpret_cast<short8*>(&rows[0][0]);
    const short8* src = reinterpret_cast<const short8*>(Db + (size_t)c * 256 * 128);
    #pragma unroll
    for (int i = 0; i < 16; ++i) {
        int idx = i * 256 + tid;
        int row = idx >> 4, ch = idx & 15;
        ldsf[row * 16 + (ch ^ (row & 15))] = src[idx];
    }

    const bool valid = dmask[c * 256 + tid] != 0;
    unsigned long long bal = __ballot(valid);
    const int before = __popcll(bal & ((1ull << lane) - 1ull));
    if (lane == 0) wcnt[wave] = __popcll(bal);
    __syncthreads();

    int base = 0, nv = 0;
    #pragma unroll
    for (int w = 0; w < 4; ++w) { int v = wcnt[w]; nv += v; if (w < wave) base += v; }
    const int myrank = valid ? (base + before) : (nv + (tid - base - before));
    const int srcrow = valid ? tid : 0;

    short8* dst = reinterpret_cast<short8*>(Db + (size_t)(c * 256 + myrank) * 128);
    #pragma unroll
    for (int i = 0; i < 16; ++i)
        dst[i] = *reinterpret_cast<const short8*>(&rows[srcrow][(i ^ (srcrow & 15)) * 8]);
}

// ---------------------------------------------------------------------------
// Kernel 2 (unchanged): out[b][c] = sum_q max_k Q[b,q,:] . Dc[c,k,:]
// Operand-swapped 32x32x16 (A=D tokens, B=Q): max over tokens is IN-LANE.
// ---------------------------------------------------------------------------
__global__ __launch_bounds__(512) void maxsim_kernel(
    const unsigned short* __restrict__ Qb, const unsigned short* __restrict__ Db,
    const int* __restrict__ dmask, float* __restrict__ out)
{
    __shared__ __align__(16) short Dlds[256][128];
    __shared__ int wcnt[4];

    const int tid = threadIdx.x;
    const int wave = tid >> 6, lane = tid & 63;
    const int lo5 = lane & 31, hi = lane >> 5;
    const int c  = blockIdx.x & 127;
    const int bg = blockIdx.x >> 7;
    const int b  = bg * 8 + wave;

    {
        const short8* src = reinterpret_cast<const short8*>(Db + (size_t)c * 256 * 128);
        #pragma unroll
        for (int i = 0; i < 8; ++i) {
            int idx = i * 512 + tid;
            int row = idx >> 4, ch = idx & 15;
            short8 v = src[row * 16 + (ch ^ (row & 15))];
            *reinterpret_cast<short8*>(&Dlds[row][ch * 8]) = v;
        }
    }
    if (tid < 256) {
        bool valid = dmask[c * 256 + tid] != 0;
        unsigned long long bal = __ballot(valid);
        if (lane == 0) wcnt[wave] = __popcll(bal);
    }
    __syncthreads();
    const int nv = wcnt[0] + wcnt[1] + wcnt[2] + wcnt[3];
    const int npairs = (nv + 63) >> 6;

    short8 a[8];
    const unsigned short* qp = Qb + ((size_t)b * 32 + lo5) * 128 + hi * 8;
    #pragma unroll
    for (int ks = 0; ks < 8; ++ks)
        a[ks] = *reinterpret_cast<const short8*>(qp + ks * 16);

    const int sw = lo5 & 15;
    float m = -1e30f;

    for (int p = 0; p < npairs; ++p) {
        f32x16 acc0 = (f32x16)(0.0f), acc1 = (f32x16)(0.0f);
        #pragma unroll
        for (int ks = 0; ks < 8; ++ks) {
            const int chs = ((2 * ks + hi) ^ sw) * 8;
            short8 d0 = *reinterpret_cast<const short8*>(&Dlds[p * 64 + lo5][chs]);
            short8 d1 = *reinterpret_cast<const short8*>(&Dlds[p * 64 + 32 + lo5][chs]);
            acc0 = MFMA32(d0, a[ks], acc0);
            acc1 = MFMA32(d1, a[ks], acc1);
        }
        #pragma unroll
        for (int r = 0; r < 16; ++r)
            m = fmaxf(m, fmaxf(acc0[r], acc1[r]));
    }

    m = fmaxf(m, __shfl_xor(m, 32));
    float s = m;
    s += __shfl_xor(s, 1);
    s += __shfl_xor(s, 2);
    s += __shfl_xor(s, 4);
    s += __shfl_xor(s, 8);
    s += __shfl_xor(s, 16);
    if (lane == 0) out[b * 128 + c] = s;
}

extern "C" void kernel_launch(void* const* d_in, const int* in_sizes, int n_in,
                              void* d_out, int out_size, void* d_ws, size_t ws_size,
                              hipStream_t stream)
{
    const float* qh    = (const float*)d_in[0];   // [128,32,768]
    const float* dh    = (const float*)d_in[1];   // [128,256,768]
    const float* W     = (const float*)d_in[2];   // [128,768]
    const int*   dmask = (const int*)d_in[3];     // [128,256]
    float* out = (float*)d_out;                   // [128,128]

    unsigned short* Qb   = (unsigned short*)d_ws;       // 4096x128 bf16 (1 MB)
    unsigned short* Db   = Qb + 4096 * 128;             // 32768x128 bf16 (8 MB)
    unsigned short* Wimg = Db + (size_t)32768 * 128;    // 12288x8 bf16 (196 KB)

    hipLaunchKernelGGL(wprep_kernel, dim3(48), dim3(256), 0, stream, W, Wimg);
    // 2304 strips of 16 rows, one wave each
    hipLaunchKernelGGL(proj_norm_kernel, dim3(2304), dim3(64), 0, stream,
                       qh, dh, Wimg, dmask, Qb, Db);
    hipLaunchKernelGGL(compact_kernel, dim3(128), dim3(256), 0, stream,
                       dmask, Db);
    hipLaunchKernelGGL(maxsim_kernel, dim3(2048), dim3(512), 0, stream,
                       Qb, Db, dmask, out);
}